// Round 3
// baseline (1360.670 us; speedup 1.0000x reference)
//
#include <hip/hip_runtime.h>
#include <cstdint>
#include <cstddef>

#define N_INS    16384
#define INS_DIM  2048
#define N_CLS    81
#define BANK     10
#define UCAP     512

// ---------------------------------------------------------------------------
// Kernel 1: per-class mean over bank + ||mean||^2 (f64)
// ---------------------------------------------------------------------------
__global__ __launch_bounds__(256)
void prep_kernel(const float* __restrict__ memory,
                 float*  __restrict__ mean_out,   // [81][2048]
                 double* __restrict__ base_out)   // [81]
{
    const int c = blockIdx.x;
    const int t = threadIdx.x;
    double nrm = 0.0;
    #pragma unroll
    for (int rep = 0; rep < 2; ++rep) {
        const int d4 = (t + rep * 256) * 4;
        float sx = 0.f, sy = 0.f, sz = 0.f, sw = 0.f;
        #pragma unroll
        for (int b = 0; b < BANK; ++b) {
            const float4 v = *(const float4*)(memory + ((size_t)(c * BANK + b)) * INS_DIM + d4);
            sx += v.x; sy += v.y; sz += v.z; sw += v.w;
        }
        sx /= 10.0f; sy /= 10.0f; sz /= 10.0f; sw /= 10.0f;
        *(float4*)(mean_out + (size_t)c * INS_DIM + d4) = make_float4(sx, sy, sz, sw);
        nrm += (double)sx * sx + (double)sy * sy + (double)sz * sz + (double)sw * sw;
    }
    #pragma unroll
    for (int o = 32; o >= 1; o >>= 1) nrm += __shfl_xor(nrm, o, 64);
    __shared__ double sred[4];
    const int w = t >> 6, lane = t & 63;
    if (lane == 0) sred[w] = nrm;
    __syncthreads();
    if (t == 0) base_out[c] = sred[0] + sred[1] + sred[2] + sred[3];
}

// ---------------------------------------------------------------------------
// Kernel 2: classification. 256 blocks x 512 thr (8 waves = 2048 waves total).
// Block = 64 instances (lane = instance). Wave w handles classes [10w,10w+10]
// (11 each, overlapping by 1 -> uniform unroll; duplicates are harmless).
// B rows are wave-uniform -> scalar loads. A staged in XOR-swizzled LDS,
// double-buffered, ONE barrier per 32-k tile, prefetch issued after barrier.
// ---------------------------------------------------------------------------
__global__ __launch_bounds__(512, 2)
void classify_kernel(const float* __restrict__ instances,
                     const int*   __restrict__ labels,
                     const float* __restrict__ mean_in,   // [81][2048]
                     const double* __restrict__ base_in,  // [81]
                     float* __restrict__ cls_out,         // [16384]
                     float* __restrict__ acc_out)         // [1]
{
    __shared__ float4 sA[2][512];   // [buf][inst*8 + swizzled k-chunk]  16 KB
    __shared__ double sS[512];      // [inst*8 + wave]
    __shared__ int    sC[512];

    const int t  = threadIdx.x;
    const int l  = t & 63;                                   // instance lane
    const int w  = __builtin_amdgcn_readfirstlane(t >> 6);   // wave id (uniform)
    const int i0 = blockIdx.x * 64;
    const int c0 = w * 10;                                   // class group start

    // staging map: thread t stages instance si, k-chunk sj (float4)
    const int si = t >> 3, sj = t & 7;
    const float* gsrc = instances + (size_t)(i0 + si) * INS_DIM + sj * 4;
    const int sdst = si * 8 + (sj ^ (si & 7));               // XOR swizzle

    double dacc[11];
    #pragma unroll
    for (int j = 0; j < 11; ++j) dacc[j] = 0.0;

    float4 g = *(const float4*)gsrc;   // ktile 0

    for (int kt = 0; kt < 64; ++kt) {
        const int pb = kt & 1;
        sA[pb][sdst] = g;
        __syncthreads();
        if (kt < 63) g = *(const float4*)(gsrc + (size_t)(kt + 1) * 32);  // after barrier

        // A fragment: lane l = instance l, 32 k-values, conflict-free b128
        float a[32];
        #pragma unroll
        for (int j = 0; j < 8; ++j)
            *(float4*)&a[j * 4] = sA[pb][l * 8 + (j ^ (l & 7))];

        const float* bbase = mean_in + (size_t)c0 * INS_DIM + kt * 32;  // uniform
        #pragma unroll
        for (int cc = 0; cc < 11; ++cc) {
            const float* bp = bbase + (size_t)cc * INS_DIM;
            float a0 = 0.f, a1 = 0.f;
            #pragma unroll
            for (int k = 0; k < 16; ++k) a0 = fmaf(a[k], bp[k], a0);
            #pragma unroll
            for (int k = 16; k < 32; ++k) a1 = fmaf(a[k], bp[k], a1);
            dacc[cc] += (double)a0 + (double)a1;
        }
        // no end-of-loop barrier needed: one barrier/iter suffices with dbuf
    }

    // local argmin over this wave's 11 classes (ascending -> first-min)
    double best = 1e300; int bc = 0x7fffffff;
    #pragma unroll
    for (int cc = 0; cc < 11; ++cc) {
        const int c = c0 + cc;
        const double sc = base_in[c] - 2.0 * dacc[cc];
        if (sc < best) { best = sc; bc = c; }
    }
    sS[l * 8 + w] = best;
    sC[l * 8 + w] = bc;
    __syncthreads();

    if (t < 64) {
        double b = sS[t * 8 + 0]; int c = sC[t * 8 + 0];
        #pragma unroll
        for (int gq = 1; gq < 8; ++gq) {
            const double v = sS[t * 8 + gq];
            if (v < b) { b = v; c = sC[t * 8 + gq]; }   // groups ascend in class order
        }
        const int gi = i0 + t;
        cls_out[gi] = (float)c;
        const bool ok = (c == labels[gi]);
        const unsigned long long m = __ballot(ok ? 1 : 0);
        if (t == 0) atomicAdd(acc_out, (float)__popcll(m) * (1.0f / 16384.0f));
    }
}

// ---------------------------------------------------------------------------
// Kernel 3: sequential per-class update. ONE WAVE per class, zero barriers.
// Whole bank (10 x 2048) register-resident: lane l holds elems j*256+l*4..+3.
// Scores: argmax ||m_s - x||^2 == argmax (||m_s||^2 - 2 m_s.x); norms kept in
// LDS (wave-uniform), updated incrementally with ||x||^2.
// ---------------------------------------------------------------------------
__global__ __launch_bounds__(64, 1)
void update_kernel(const float* __restrict__ instances,
                   const int*   __restrict__ labels,
                   const float* __restrict__ memory,
                   const int*   __restrict__ memory_pos,
                   float* __restrict__ mem_out,   // [81][10][2048]
                   float* __restrict__ pos_out)   // [81]
{
    __shared__ int    s_list[UCAP];
    __shared__ double s_norm[BANK];

    const int c = blockIdx.x;
    const int l = threadIdx.x;     // 0..63, single wave
    const unsigned long long below = (1ull << l) - 1ull;

    // ---- Phase 1: stable compaction of indices with label==c (4/lane/iter)
    int cnt = 0;
    for (int base = 0; base < N_INS; base += 256) {
        const int4 lv = *(const int4*)(labels + base + l * 4);
        const bool q0 = (lv.x == c), q1 = (lv.y == c), q2 = (lv.z == c), q3 = (lv.w == c);
        const unsigned long long b0 = __ballot(q0), b1 = __ballot(q1),
                                 b2 = __ballot(q2), b3 = __ballot(q3);
        const int preL = (int)(__popcll(b0 & below) + __popcll(b1 & below) +
                               __popcll(b2 & below) + __popcll(b3 & below));
        int pos = cnt + preL;
        if (q0) { if (pos < UCAP) s_list[pos] = base + 4 * l + 0; ++pos; }
        if (q1) { if (pos < UCAP) s_list[pos] = base + 4 * l + 1; ++pos; }
        if (q2) { if (pos < UCAP) s_list[pos] = base + 4 * l + 2; ++pos; }
        if (q3) { if (pos < UCAP) s_list[pos] = base + 4 * l + 3; ++pos; }
        cnt += (int)(__popcll(b0) + __popcll(b1) + __popcll(b2) + __popcll(b3));
    }
    if (cnt > UCAP) cnt = UCAP;

    // ---- Phase 2: bank -> registers; initial slot norms -> LDS
    float4 m[BANK][8];
    #pragma unroll
    for (int s = 0; s < BANK; ++s)
        #pragma unroll
        for (int j = 0; j < 8; ++j)
            m[s][j] = *(const float4*)(memory + ((size_t)(c * BANK + s)) * INS_DIM + j * 256 + l * 4);

    {
        double nv[BANK];
        #pragma unroll
        for (int s = 0; s < BANK; ++s) {
            float a0 = 0.f, a1 = 0.f;
            #pragma unroll
            for (int j = 0; j < 4; ++j) {
                a0 = fmaf(m[s][j].x, m[s][j].x, a0); a0 = fmaf(m[s][j].y, m[s][j].y, a0);
                a0 = fmaf(m[s][j].z, m[s][j].z, a0); a0 = fmaf(m[s][j].w, m[s][j].w, a0);
            }
            #pragma unroll
            for (int j = 4; j < 8; ++j) {
                a1 = fmaf(m[s][j].x, m[s][j].x, a1); a1 = fmaf(m[s][j].y, m[s][j].y, a1);
                a1 = fmaf(m[s][j].z, m[s][j].z, a1); a1 = fmaf(m[s][j].w, m[s][j].w, a1);
            }
            nv[s] = (double)a0 + (double)a1;
        }
        #pragma unroll
        for (int o = 32; o >= 1; o >>= 1)
            #pragma unroll
            for (int s = 0; s < BANK; ++s) nv[s] += __shfl_xor(nv[s], o, 64);
        if (l == 0) {
            #pragma unroll
            for (int s = 0; s < BANK; ++s) s_norm[s] = nv[s];
        }
    }

    int p = memory_pos[c];

    // ---- Phase 3: the serial scan (no barriers; prefetch double-buffer)
    float4 xa[8], xb[8];
    #pragma unroll
    for (int j = 0; j < 8; ++j) { xa[j] = make_float4(0,0,0,0); xb[j] = make_float4(0,0,0,0); }
    int idx_next = 0;
    if (cnt > 0) {
        const float* xp = instances + (size_t)s_list[0] * INS_DIM;
        #pragma unroll
        for (int j = 0; j < 8; ++j) xa[j] = *(const float4*)(xp + j * 256 + l * 4);
        idx_next = (cnt > 1) ? s_list[1] : s_list[0];
    }

    auto stepf = [&](float4 (&xc)[8], float4 (&xn)[8], const int ii) {
        // prefetch next instance (address computed last step; no LDS in path)
        const float* np_ = instances + (size_t)idx_next * INS_DIM;
        #pragma unroll
        for (int j = 0; j < 8; ++j) xn[j] = *(const float4*)(np_ + j * 256 + l * 4);
        idx_next = s_list[(ii + 2 < cnt) ? (ii + 2) : (cnt - 1)];  // broadcast read

        // 10 slot dots + ||x||^2, f32 16-chunks folded to f64
        double d[BANK + 1];
        #pragma unroll
        for (int s = 0; s < BANK; ++s) {
            float a0 = 0.f, a1 = 0.f;
            #pragma unroll
            for (int j = 0; j < 4; ++j) {
                a0 = fmaf(m[s][j].x, xc[j].x, a0); a0 = fmaf(m[s][j].y, xc[j].y, a0);
                a0 = fmaf(m[s][j].z, xc[j].z, a0); a0 = fmaf(m[s][j].w, xc[j].w, a0);
            }
            #pragma unroll
            for (int j = 4; j < 8; ++j) {
                a1 = fmaf(m[s][j].x, xc[j].x, a1); a1 = fmaf(m[s][j].y, xc[j].y, a1);
                a1 = fmaf(m[s][j].z, xc[j].z, a1); a1 = fmaf(m[s][j].w, xc[j].w, a1);
            }
            d[s] = (double)a0 + (double)a1;
        }
        {
            float a0 = 0.f, a1 = 0.f;
            #pragma unroll
            for (int j = 0; j < 4; ++j) {
                a0 = fmaf(xc[j].x, xc[j].x, a0); a0 = fmaf(xc[j].y, xc[j].y, a0);
                a0 = fmaf(xc[j].z, xc[j].z, a0); a0 = fmaf(xc[j].w, xc[j].w, a0);
            }
            #pragma unroll
            for (int j = 4; j < 8; ++j) {
                a1 = fmaf(xc[j].x, xc[j].x, a1); a1 = fmaf(xc[j].y, xc[j].y, a1);
                a1 = fmaf(xc[j].z, xc[j].z, a1); a1 = fmaf(xc[j].w, xc[j].w, a1);
            }
            d[BANK] = (double)a0 + (double)a1;
        }
        #pragma unroll
        for (int o = 32; o >= 1; o >>= 1)
            #pragma unroll
            for (int v = 0; v < BANK + 1; ++v) d[v] += __shfl_xor(d[v], o, 64);

        int widx;
        if (p < BANK) {
            widx = p;
        } else {
            double bv = s_norm[0] - 2.0 * d[0]; widx = 0;
            #pragma unroll
            for (int s = 1; s < BANK; ++s) {
                const double v = s_norm[s] - 2.0 * d[s];
                if (v > bv) { bv = v; widx = s; }   // strict > : first-max
            }
        }
        const int sw = __builtin_amdgcn_readfirstlane(widx);  // uniform -> scalar branch
        #pragma unroll
        for (int s = 0; s < BANK; ++s) {
            if (sw == s) {
                #pragma unroll
                for (int j = 0; j < 8; ++j) m[s][j] = xc[j];
            }
        }
        if (l == 0) s_norm[sw] = d[BANK];
        if (p < BANK) ++p;
    };

    int ii = 0;
    while (ii < cnt) {
        stepf(xa, xb, ii); ++ii;
        if (ii >= cnt) break;
        stepf(xb, xa, ii); ++ii;
    }

    // ---- Phase 4: write bank + pos
    #pragma unroll
    for (int s = 0; s < BANK; ++s)
        #pragma unroll
        for (int j = 0; j < 8; ++j)
            *(float4*)(mem_out + ((size_t)(c * BANK + s)) * INS_DIM + j * 256 + l * 4) = m[s][j];
    if (l == 0) pos_out[c] = (float)p;
}

// ---------------------------------------------------------------------------
extern "C" void kernel_launch(void* const* d_in, const int* in_sizes, int n_in,
                              void* d_out, int out_size, void* d_ws, size_t ws_size,
                              hipStream_t stream)
{
    const float* instances = (const float*)d_in[0];
    const int*   labels    = (const int*)  d_in[1];
    const float* memory    = (const float*)d_in[2];
    const int*   mpos      = (const int*)  d_in[3];

    float* out      = (float*)d_out;
    float* cls_out  = out;                                      // [16384]
    float* acc_out  = out + N_INS;                              // [1]
    float* mem_out  = out + N_INS + 1;                          // [81*10*2048]
    float* pos_out  = mem_out + (size_t)N_CLS * BANK * INS_DIM; // [81]

    // scratch inside new_mem output region; update_kernel overwrites it last.
    // base at odd float offset 165889 so its byte address is 8-aligned.
    float*  mean_scr = mem_out;                                 // [81*2048]
    double* base_scr = (double*)(mem_out + (size_t)N_CLS * INS_DIM + 1);

    hipMemsetAsync(acc_out, 0, sizeof(float), stream);
    hipLaunchKernelGGL(prep_kernel, dim3(N_CLS), dim3(256), 0, stream,
                       memory, mean_scr, base_scr);
    hipLaunchKernelGGL(classify_kernel, dim3(N_INS / 64), dim3(512), 0, stream,
                       instances, labels, mean_scr, base_scr, cls_out, acc_out);
    hipLaunchKernelGGL(update_kernel, dim3(N_CLS), dim3(64), 0, stream,
                       instances, labels, memory, mpos, mem_out, pos_out);
}